// Round 3
// baseline (516.439 us; speedup 1.0000x reference)
//
#include <hip/hip_runtime.h>

// ---------------- problem constants ----------------
#define NNODES 200
#define FEATX  2600      // 50*52
#define FEAT   2800      // FEATX + NNODES
#define NCH    44        // 44 * 64 = 2816 padded K
#define NGRP   11        // 11 superphases x 4 chunks
#define N1     128

typedef _Float16 f16;
typedef _Float16 f16x8 __attribute__((ext_vector_type(8)));
typedef float    f32x4 __attribute__((ext_vector_type(4)));

// ---------------- workspace byte offsets ----------------
#define W1T_OFF   0u          // 44 * 16384 = 720896  (swizzled fp16 W1^T chunks)
#define W2T_OFF   720896u     // 32768 (swizzled fp16 W2^T)
#define W3T_OFF   753664u     // 16384 (swizzled fp16 W3^T)
#define WG_OFF    770048u     // 200*128*4 = 102400 (fp32 Wg')
#define B1P_OFF   872448u     // 512   (fp32 folded bias b1')
#define HW_OFF    872960u     // 16    (fp32 hw_val[3])

__device__ __forceinline__ void gl_lds16(const void* g, void* l) {
  __builtin_amdgcn_global_load_lds(
      (const __attribute__((address_space(1))) unsigned int*)g,
      (__attribute__((address_space(3))) unsigned int*)l, 16, 0, 0);
}

// ============ prep: norms, hw, edge weights, Wg' (edge-parallel LDS atomics),
//              folded b1' — ONE block, all phases sync'd by __syncthreads ======
__global__ __launch_bounds__(256)
void prep(const int* __restrict__ esrc, const int* __restrict__ edst,
          const float* __restrict__ emb, const float* __restrict__ gcw,
          const float* __restrict__ gcb, const float* __restrict__ W1,
          const float* __restrict__ b1, char* __restrict__ ws) {
  __shared__ float dg[2][256];
  __shared__ int   se[800];
  __shared__ int   sd[800];
  __shared__ float swe[800];
  __shared__ float wga[NNODES * N1];   // 102400 B
  __shared__ float red[256];
  const int tid = threadIdx.x;  // 256

  for (int i = tid; i < 512; i += 256) ((float*)dg)[i] = 0.f;
  for (int i = tid; i < NNODES * N1; i += 256) wga[i] = 0.f;
  __syncthreads();
  for (int e = tid; e < 800; e += 256) {
    const int s = esrc[e], d = edst[e];
    se[e] = s; sd[e] = d;
    atomicAdd(&dg[0][s], 1.f);
    atomicAdd(&dg[1][d], 1.f);
  }
  __syncthreads();
  for (int i = tid; i < 512; i += 256) {
    float* p = (float*)dg + i;
    *p = 1.f / sqrtf(fmaxf(*p, 1.f));
  }
  if (tid < 3) {
    float s = 0.f;
    for (int q = 0; q < 5; ++q) s += emb[tid * 5 + q] * gcw[q];
    ((float*)(ws + HW_OFF))[tid] = s;
  }
  __syncthreads();
  for (int e = tid; e < 800; e += 256)
    swe[e] = dg[0][se[e]] * dg[1][sd[e]];
  __syncthreads();

  // Wg'[n,j] = sum_{e: src==n} we[e] * W1g[dst, j]  (edge-parallel, LDS atomics)
  const int j = tid & 127, h = tid >> 7;
  for (int e = h; e < 800; e += 2) {
    const float v = swe[e] * W1[(FEATX + sd[e]) * N1 + j];
    atomicAdd(&wga[se[e] * N1 + j], v);
  }

  // b1'[j] = b1[j] + gcb * sum_d W1g[d, j]   (parallel fold + LDS reduce)
  {
    float s = 0.f;
    for (int d = h; d < NNODES; d += 2)
      s += W1[(FEATX + d) * N1 + j];
    red[tid] = s;
    __syncthreads();   // also completes wga atomics
    if (h == 0)
      ((float*)(ws + B1P_OFF))[j] = b1[j] + gcb[0] * (red[j] + red[128 + j]);
  }
  __syncthreads();
  float4* dst = (float4*)(ws + WG_OFF);
  for (int i = tid; i < NNODES * N1 / 4; i += 256) dst[i] = ((const float4*)wga)[i];
}

// ============ pack: coalesced read -> LDS transpose/swizzle -> coalesced write ====
__global__ void pack(const float* __restrict__ W1, const float* __restrict__ W2,
                     const float* __restrict__ W3, char* __restrict__ ws) {
  __shared__ __align__(16) char tile[32768];
  const int bid = blockIdx.x, tid = threadIdx.x;  // 46 x 256
  if (bid < NCH) {
    const float* wg = (const float*)(ws + WG_OFF);
    const int c = tid & 127, kh = tid >> 7;
    for (int kk = kh; kk < 64; kk += 2) {
      const int k = bid * 64 + kk;
      float v;
      if (k < FEATX) v = W1[k * N1 + c];
      else if (k < FEAT) v = wg[(k - FEATX) * N1 + c];
      else v = 0.f;
      *(f16*)(tile + ((c * 128 + kk * 2) ^ ((c & 7) << 4))) = (f16)v;
    }
    __syncthreads();
    char* dst = ws + W1T_OFF + bid * 16384;
    for (int i = 0; i < 4; ++i)
      *(uint4*)(dst + tid * 16 + i * 4096) = *(const uint4*)(tile + tid * 16 + i * 4096);
  } else if (bid == NCH) {
    const int c = tid & 127, kh = tid >> 7;
    for (int k = kh; k < 128; k += 2) {
      const float v = W2[k * 128 + c];
      *(f16*)(tile + ((c * 256 + k * 2) ^ ((c & 7) << 4))) = (f16)v;
    }
    __syncthreads();
    char* dst = ws + W2T_OFF;
    for (int i = 0; i < 8; ++i)
      *(uint4*)(dst + tid * 16 + i * 4096) = *(const uint4*)(tile + tid * 16 + i * 4096);
  } else {
    const int c = tid & 63, kh = tid >> 6;
    for (int k = kh; k < 128; k += 4) {
      const float v = W3[k * 64 + c];
      *(f16*)(tile + ((c * 256 + k * 2) ^ ((c & 7) << 4))) = (f16)v;
    }
    __syncthreads();
    char* dst = ws + W3T_OFF;
    for (int i = 0; i < 4; ++i)
      *(uint4*)(dst + tid * 16 + i * 4096) = *(const uint4*)(tile + tid * 16 + i * 4096);
  }
}

// ============ fused main ============
// Superphase structure: B staged in groups of 4 chunks (64KB, double-buffered);
// ONE barrier + counted vmcnt(8) per superphase (11 total). A loaded direct to
// registers 2 phases ahead (named slots). Waves drift freely between barriers.
__global__ __launch_bounds__(512, 2)
void fused_main(const float* __restrict__ x, const int* __restrict__ apps,
                const char* __restrict__ ws, const float* __restrict__ b2,
                const float* __restrict__ b3, const float* __restrict__ W4,
                const float* __restrict__ b4, float* __restrict__ out) {
  __shared__ __align__(16) char lds[131072];
  // loop: group buffers at lds + (g&1)*65536
  // epilogue: W23 at lds[0..49152), Act1 [49152..65536), Act2 [65536..81920)
  char*  sAct1 = lds + 49152;
  char*  sAct2 = lds + 65536;
  float* sAct3 = (float*)(lds + 49152);   // aliases Act1 region after GEMM3 barrier

  const int tid  = threadIdx.x;
  const int lane = tid & 63;
  const int w    = tid >> 6;     // 0..7
  const int lrow = lane & 15;
  const int lk   = lane >> 4;    // 0..3
  const int wr   = w >> 1;       // 0..3  (16-row slice)
  const int wc   = w & 1;        // 0..1  (64-col slice)
  const int blk  = blockIdx.x;

  const float* hwv = (const float*)(ws + HW_OFF);
  const float hw0 = hwv[0], hw1 = hwv[1], hw2 = hwv[2];

  const int row_g = blk * 64 + wr * 16 + lrow;
  const float* xrow = x + (size_t)row_g * FEATX;
  const int*   irow = apps + (size_t)row_g * NNODES;

  int boff[2][4];
#pragma unroll
  for (int ks = 0; ks < 2; ++ks)
#pragma unroll
    for (int f = 0; f < 4; ++f) {
      const int c = wc * 64 + f * 16 + lrow;
      boff[ks][f] = ((c * 128 + ks * 64 + lk * 16) ^ ((lrow & 7) << 4));
    }

  const f32x4 zed = {0.f, 0.f, 0.f, 0.f};
  f32x4 acc1[4] = {zed, zed, zed, zed};

  auto issueG = [&](int g) {   // stage chunks 4g..4g+3 into buffer g&1
    const int gg = (g > NGRP - 1) ? NGRP - 1 : g;
    const char* src = ws + W1T_OFF + (size_t)(gg * 4) * 16384;
    char* dst = lds + (g & 1) * 65536;
#pragma unroll
    for (int r = 0; r < 8; ++r) {
      const int o = r * 8192 + w * 1024;
      gl_lds16(src + o + lane * 16, dst + o);
    }
  };
  auto issueA = [&](int tc, uint4 (&ar)[2][2]) {
#pragma unroll
    for (int ks = 0; ks < 2; ++ks) {
      const int k0 = tc * 64 + ks * 32 + lk * 8;
      const char* p;
      if (k0 + 8 <= FEATX)  p = (const char*)(xrow + k0);
      else if (k0 < FEAT)   p = (const char*)(irow + (k0 - FEATX));
      else                  p = (const char*)xrow;   // dummy safe addr, zeroed at cvt
      ar[ks][0] = *(const uint4*)p;
      ar[ks][1] = *(const uint4*)(p + 16);
    }
  };
  auto cvtA = [&](int t, const uint4 (&ar)[2][2], f16x8 (&af)[2]) {
#pragma unroll
    for (int ks = 0; ks < 2; ++ks) {
      const int k0 = t * 64 + ks * 32 + lk * 8;
      union { uint4 u[2]; unsigned ui[8]; float f[8]; } d;
      d.u[0] = ar[ks][0]; d.u[1] = ar[ks][1];
      union { f16x8 v; f16 h[8]; } r;
      if (k0 + 8 <= FEATX) {
#pragma unroll
        for (int j2 = 0; j2 < 8; ++j2) r.h[j2] = (f16)d.f[j2];
      } else if (k0 < FEAT) {
#pragma unroll
        for (int j2 = 0; j2 < 8; ++j2) {
          const unsigned a = d.ui[j2];
          r.h[j2] = (f16)(a == 0u ? hw0 : (a == 1u ? hw1 : hw2));
        }
      } else {
#pragma unroll
        for (int j2 = 0; j2 < 8; ++j2) r.h[j2] = (f16)0.f;
      }
      af[ks] = r.v;
    }
  };
  auto compute = [&](const f16x8 (&af)[2], const char* b) {
#pragma unroll
    for (int ks = 0; ks < 2; ++ks)
#pragma unroll
      for (int f = 0; f < 4; ++f) {
        const f16x8 bf = *(const f16x8*)(b + boff[ks][f]);
        acc1[f] = __builtin_amdgcn_mfma_f32_16x16x32_f16(af[ks], bf, acc1[f], 0, 0, 0);
      }
  };

  uint4 arA[2][2], arB[2][2];
  f16x8 af[2];

  // prologue: group 0 + first two A phases in flight
  issueG(0);
  __builtin_amdgcn_sched_barrier(0);
  issueA(0, arA);
  issueA(1, arB);
  __builtin_amdgcn_sched_barrier(0);

  for (int g = 0; g < NGRP; ++g) {
    asm volatile("s_waitcnt vmcnt(8)" ::: "memory");  // drain group g, keep 8 A-loads
    __builtin_amdgcn_s_barrier();
    __builtin_amdgcn_sched_barrier(0);
    issueG(g + 1);
    __builtin_amdgcn_sched_barrier(0);
    const char* bb = lds + (g & 1) * 65536;
    const int t0 = 4 * g;
    // p0
    cvtA(t0 + 0, arA, af); issueA(t0 + 2, arA);
    __builtin_amdgcn_sched_barrier(0);
    compute(af, bb);
    // p1
    cvtA(t0 + 1, arB, af); issueA(t0 + 3, arB);
    __builtin_amdgcn_sched_barrier(0);
    compute(af, bb + 16384);
    // p2
    cvtA(t0 + 2, arA, af); issueA(t0 + 4, arA);
    __builtin_amdgcn_sched_barrier(0);
    compute(af, bb + 32768);
    // p3
    cvtA(t0 + 3, arB, af); issueA(t0 + 5, arB);
    __builtin_amdgcn_sched_barrier(0);
    compute(af, bb + 49152);
  }
  __syncthreads();   // drains ALL outstanding vmem (incl. dummy loads)

  // prefetch W2^T + W3^T (48KB contiguous in ws) into lds[0..49152)
#pragma unroll
  for (int r = 0; r < 6; ++r) {
    const int o = r * 8192 + w * 1024;
    gl_lds16(ws + W2T_OFF + o + lane * 16, lds + o);
  }

  // -------- epilogue 1: + b1', softplus -> sAct1 (f16, 256B rows, swizzled) ----
  const float* b1p = (const float*)(ws + B1P_OFF);
#pragma unroll
  for (int f = 0; f < 4; ++f) {
    const int col = wc * 64 + f * 16 + lrow;
    const float bb = b1p[col];
#pragma unroll
    for (int r = 0; r < 4; ++r) {
      const int row = wr * 16 + lk * 4 + r;
      float v = acc1[f][r] + bb;
      v = fmaxf(v, 0.f) + log1pf(expf(-fabsf(v)));
      *(f16*)(sAct1 + ((row * 256 + col * 2) ^ ((row & 7) << 4))) = (f16)v;
    }
  }
  __syncthreads();   // drains W23 gl_lds + act1 writes

  // -------- GEMM2: a1[64x128] @ W2[128x128], softplus -> sAct2 --------
  f32x4 acc2[4] = {zed, zed, zed, zed};
#pragma unroll
  for (int ks = 0; ks < 4; ++ks) {
    const int ar = wr * 16 + lrow;
    const f16x8 a2 = *(const f16x8*)(sAct1 + ((ar * 256 + ks * 64 + lk * 16) ^ ((lrow & 7) << 4)));
#pragma unroll
    for (int f = 0; f < 4; ++f) {
      const int c = wc * 64 + f * 16 + lrow;
      const f16x8 bf = *(const f16x8*)(lds + ((c * 256 + ks * 64 + lk * 16) ^ ((lrow & 7) << 4)));
      acc2[f] = __builtin_amdgcn_mfma_f32_16x16x32_f16(a2, bf, acc2[f], 0, 0, 0);
    }
  }
#pragma unroll
  for (int f = 0; f < 4; ++f) {
    const int col = wc * 64 + f * 16 + lrow;
    const float bb = b2[col];
#pragma unroll
    for (int r = 0; r < 4; ++r) {
      const int row = wr * 16 + lk * 4 + r;
      float v = acc2[f][r] + bb;
      v = fmaxf(v, 0.f) + log1pf(expf(-fabsf(v)));
      *(f16*)(sAct2 + ((row * 256 + col * 2) ^ ((row & 7) << 4))) = (f16)v;
    }
  }
  __syncthreads();

  // -------- GEMM3: a2[64x128] @ W3[128x64], tanhshrink -> sAct3 (fp32) --------
  f32x4 acc3[2] = {zed, zed};
  const char* w3p = lds + 32768;
#pragma unroll
  for (int ks = 0; ks < 4; ++ks) {
    const int ar = wr * 16 + lrow;
    const f16x8 a3 = *(const f16x8*)(sAct2 + ((ar * 256 + ks * 64 + lk * 16) ^ ((lrow & 7) << 4)));
#pragma unroll
    for (int f = 0; f < 2; ++f) {
      const int c = wc * 32 + f * 16 + lrow;
      const f16x8 bf = *(const f16x8*)(w3p + ((c * 256 + ks * 64 + lk * 16) ^ ((lrow & 7) << 4)));
      acc3[f] = __builtin_amdgcn_mfma_f32_16x16x32_f16(a3, bf, acc3[f], 0, 0, 0);
    }
  }
  __syncthreads();   // Act2 reads done; Act3 region (aliases Act1) free to write
#pragma unroll
  for (int f = 0; f < 2; ++f) {
    const int col = wc * 32 + f * 16 + lrow;
    const float bb = b3[col];
#pragma unroll
    for (int r = 0; r < 4; ++r) {
      const int row = wr * 16 + lk * 4 + r;
      const float z = acc3[f][r] + bb;
      sAct3[row * 64 + col] = z - tanhf(z);
    }
  }
  __syncthreads();

  // -------- GEMM4 (vector fp32): a3[64x64] @ W4[64x2] + b4, sigmoid --------
  if (tid < 256) {
    const int row = tid >> 2, q = tid & 3;
    float a0 = 0.f, a1 = 0.f;
#pragma unroll
    for (int k = q * 16; k < q * 16 + 16; k += 2) {
      const float2 a = *(const float2*)(&sAct3[row * 64 + k]);
      const float4 wv = *(const float4*)(W4 + k * 2);
      a0 += a.x * wv.x + a.y * wv.z;
      a1 += a.x * wv.y + a.y * wv.w;
    }
    a0 += __shfl_down(a0, 1); a1 += __shfl_down(a1, 1);
    a0 += __shfl_down(a0, 2); a1 += __shfl_down(a1, 2);
    if (q == 0) {
      float2 o;
      o.x = 1.f / (1.f + expf(-(a0 + b4[0])));
      o.y = 1.f / (1.f + expf(-(a1 + b4[1])));
      *(float2*)(out + (size_t)(blk * 64 + row) * 2) = o;
    }
  }
}

// ---------------- launch ----------------
extern "C" void kernel_launch(void* const* d_in, const int* in_sizes, int n_in,
                              void* d_out, int out_size, void* d_ws, size_t ws_size,
                              hipStream_t stream) {
  const float* x    = (const float*)d_in[0];
  const int*   apps = (const int*)d_in[1];
  const int*   esrc = (const int*)d_in[2];
  const int*   edst = (const int*)d_in[3];
  const float* emb  = (const float*)d_in[4];
  const float* gcw  = (const float*)d_in[5];
  const float* gcb  = (const float*)d_in[6];
  const float* W1   = (const float*)d_in[7];
  const float* b1   = (const float*)d_in[8];
  const float* W2   = (const float*)d_in[9];
  const float* b2   = (const float*)d_in[10];
  const float* W3   = (const float*)d_in[11];
  const float* b3   = (const float*)d_in[12];
  const float* W4   = (const float*)d_in[13];
  const float* b4   = (const float*)d_in[14];
  char* ws = (char*)d_ws;
  float* out = (float*)d_out;

  hipLaunchKernelGGL(prep, dim3(1), dim3(256), 0, stream,
                     esrc, edst, emb, gcw, gcb, W1, b1, ws);
  hipLaunchKernelGGL(pack, dim3(46), dim3(256), 0, stream, W1, W2, W3, ws);
  hipLaunchKernelGGL(fused_main, dim3(256), dim3(512), 0, stream,
                     x, apps, ws, b2, b3, W4, b4, out);
}

// Round 4
// 379.179 us; speedup vs baseline: 1.3620x; 1.3620x over previous
//
#include <hip/hip_runtime.h>

// ---------------- problem constants ----------------
#define NNODES 200
#define FEATX  2600      // 50*52
#define FEAT   2800      // FEATX + NNODES
#define NC     88        // 88 K-chunks of 32 -> K padded to 2816
#define N1     128

typedef _Float16 f16;
typedef _Float16 f16x8 __attribute__((ext_vector_type(8)));
typedef float    f32x4 __attribute__((ext_vector_type(4)));

// ---------------- workspace byte offsets ----------------
// W1P: 88 chunks x 8KB, fragment-ordered: [chunk][f(8)][lane(64)][8 f16]
//      value = B[k = chunk*32 + (lane>>4)*8 + j][col = f*16 + (lane&15)]
#define W1P_OFF   0u          // 720896
#define W2P_OFF   720896u     // 4 chunks x 8KB = 32768
#define W3P_OFF   753664u     // 4 chunks x 4KB = 16384 (4 col-frags)
#define WG_OFF    770048u     // 200*128 f16 = 51200
#define B1P_OFF   821248u     // 512
#define HW_OFF    821760u     // 32
#define CSRP_OFF  821792u     // 201*4 -> 816
#define CSRD_OFF  822608u     // 800*4
#define CSRW_OFF  825808u     // 800*4  (end 829008)

// ============ prepA: norms, hw, CSR(by src), b1' ============
__global__ __launch_bounds__(256)
void prepA(const int* __restrict__ esrc, const int* __restrict__ edst,
           const float* __restrict__ emb, const float* __restrict__ gcw,
           const float* __restrict__ gcb, const float* __restrict__ W1,
           const float* __restrict__ b1, char* __restrict__ ws) {
  __shared__ float dgo[NNODES], dgi[NNODES];
  __shared__ int   ssrc[800], sdst[800];
  __shared__ int   cnt[NNODES], cur[NNODES];
  __shared__ int   ps[256];
  __shared__ float red[256];
  const int tid = threadIdx.x;  // 256

  if (tid < NNODES) { dgo[tid] = 0.f; dgi[tid] = 0.f; cnt[tid] = 0; cur[tid] = 0; }
  __syncthreads();
  for (int e = tid; e < 800; e += 256) {
    const int s = esrc[e], d = edst[e];
    ssrc[e] = s; sdst[e] = d;
    atomicAdd(&dgo[s], 1.f);
    atomicAdd(&dgi[d], 1.f);
    atomicAdd(&cnt[s], 1);
  }
  __syncthreads();
  if (tid < NNODES) {
    dgo[tid] = 1.f / sqrtf(fmaxf(dgo[tid], 1.f));
    dgi[tid] = 1.f / sqrtf(fmaxf(dgi[tid], 1.f));
  }
  if (tid < 3) {
    float s = 0.f;
    for (int q = 0; q < 5; ++q) s += emb[tid * 5 + q] * gcw[q];
    ((float*)(ws + HW_OFF))[tid] = s;
  }
  // inclusive prefix sum of cnt over 256 slots (Hillis-Steele)
  ps[tid] = (tid < NNODES) ? cnt[tid] : 0;
  __syncthreads();
  for (int off = 1; off < 256; off <<= 1) {
    const int v = (tid >= off) ? ps[tid - off] : 0;
    __syncthreads();
    ps[tid] += v;
    __syncthreads();
  }
  int* rp = (int*)(ws + CSRP_OFF);
  if (tid < NNODES) rp[tid] = ps[tid] - cnt[tid];
  if (tid == NNODES) rp[NNODES] = 800;
  __syncthreads();
  // scatter edges into CSR (grouped by src)
  int*   cd = (int*)(ws + CSRD_OFF);
  float* cw = (float*)(ws + CSRW_OFF);
  for (int e = tid; e < 800; e += 256) {
    const int s = ssrc[e], d = sdst[e];
    const int pos = (ps[s] - cnt[s]) + atomicAdd(&cur[s], 1);
    cd[pos] = d;
    cw[pos] = dgo[s] * dgi[d];
  }
  // b1'[j] = b1[j] + gcb * sum_d W1g[d, j]
  {
    const int j = tid & 127, h = tid >> 7;
    float s = 0.f;
    for (int d = h; d < NNODES; d += 2)
      s += W1[(FEATX + d) * N1 + j];
    red[tid] = s;
    __syncthreads();
    if (h == 0)
      ((float*)(ws + B1P_OFF))[j] = b1[j] + gcb[0] * (red[j] + red[128 + j]);
  }
}

// ============ prepWg: per-node CSR gather, write f16 Wg' ============
__global__ __launch_bounds__(128)
void prepWg(const float* __restrict__ W1, char* __restrict__ ws) {
  const int n = blockIdx.x;      // 0..199
  const int j = threadIdx.x;     // 0..127
  const int* rp   = (const int*)(ws + CSRP_OFF);
  const int* cd   = (const int*)(ws + CSRD_OFF);
  const float* cw = (const float*)(ws + CSRW_OFF);
  const int e0 = rp[n], e1 = rp[n + 1];
  float acc = 0.f;
  for (int e = e0; e < e1; ++e)
    acc += cw[e] * W1[(FEATX + cd[e]) * N1 + j];
  ((f16*)(ws + WG_OFF))[n * N1 + j] = (f16)acc;
}

// ============ pack: LDS transpose -> fragment-ordered f16 ============
__global__ __launch_bounds__(256)
void pack(const float* __restrict__ W1, const float* __restrict__ W2,
          const float* __restrict__ W3, char* __restrict__ ws) {
  __shared__ __align__(16) float T[32 * 128];   // 16KB
  const int bid = blockIdx.x, tid = threadIdx.x;  // 96 x 256
  const f16* wg = (const f16*)(ws + WG_OFF);
  if (bid < NC) {
    const int k0 = bid * 32;
#pragma unroll
    for (int i = 0; i < 4; ++i) {
      const int p = i * 1024 + tid * 4;
      const int r = p >> 7, c = p & 127;
      const int k = k0 + r;
      float4 v;
      if (k < FEATX) v = *(const float4*)(W1 + (size_t)k * N1 + c);
      else if (k < FEAT) {
        const f16* g = wg + (k - FEATX) * N1 + c;
        v.x = (float)g[0]; v.y = (float)g[1]; v.z = (float)g[2]; v.w = (float)g[3];
      } else { v.x = v.y = v.z = v.w = 0.f; }
      *(float4*)(&T[r * 128 + c]) = v;
    }
    __syncthreads();
    char* dst = ws + W1P_OFF + (size_t)bid * 8192;
    for (int s = tid; s < 512; s += 256) {
      const int f = s >> 6, lx = s & 63;
      const int colb = f * 16 + (lx & 15), kb = (lx >> 4) * 8;
      union { f16x8 v; f16 h[8]; } u;
#pragma unroll
      for (int j = 0; j < 8; ++j) u.h[j] = (f16)T[(kb + j) * 128 + colb];
      *(f16x8*)(dst + f * 1024 + lx * 16) = u.v;
    }
  } else if (bid < 92) {
    const int cc = bid - 88, k0 = cc * 32;
#pragma unroll
    for (int i = 0; i < 4; ++i) {
      const int p = i * 1024 + tid * 4;
      const int r = p >> 7, c = p & 127;
      *(float4*)(&T[r * 128 + c]) = *(const float4*)(W2 + (size_t)(k0 + r) * 128 + c);
    }
    __syncthreads();
    char* dst = ws + W2P_OFF + (size_t)cc * 8192;
    for (int s = tid; s < 512; s += 256) {
      const int f = s >> 6, lx = s & 63;
      const int colb = f * 16 + (lx & 15), kb = (lx >> 4) * 8;
      union { f16x8 v; f16 h[8]; } u;
#pragma unroll
      for (int j = 0; j < 8; ++j) u.h[j] = (f16)T[(kb + j) * 128 + colb];
      *(f16x8*)(dst + f * 1024 + lx * 16) = u.v;
    }
  } else {
    const int cc = bid - 92, k0 = cc * 32;
#pragma unroll
    for (int i = 0; i < 2; ++i) {
      const int p = i * 1024 + tid * 4;
      const int r = p >> 6, c = p & 63;
      *(float4*)(&T[r * 64 + c]) = *(const float4*)(W3 + (size_t)(k0 + r) * 64 + c);
    }
    __syncthreads();
    char* dst = ws + W3P_OFF + (size_t)cc * 4096;
    {
      const int s = tid;                       // 4 frags x 64 lanes = 256 slots
      const int f = s >> 6, lx = s & 63;
      const int colb = f * 16 + (lx & 15), kb = (lx >> 4) * 8;
      union { f16x8 v; f16 h[8]; } u;
#pragma unroll
      for (int j = 0; j < 8; ++j) u.h[j] = (f16)T[(kb + j) * 64 + colb];
      *(f16x8*)(dst + f * 1024 + lx * 16) = u.v;
    }
  }
}

// ============ fused main: 1 wave/block, 32 rows, no barriers, no K-loop LDS ====
__global__ __launch_bounds__(64)
void fused_main(const float* __restrict__ x, const int* __restrict__ apps,
                const char* __restrict__ ws, const float* __restrict__ b2,
                const float* __restrict__ b3, const float* __restrict__ W4,
                const float* __restrict__ b4, float* __restrict__ out) {
  __shared__ __align__(16) char lds[8192];
  const int l   = threadIdx.x;   // 0..63
  const int blk = blockIdx.x;    // 0..511
  const int lm  = l & 15, lg = l >> 4;
  const int row0 = blk * 32;

  const float* hwv = (const float*)(ws + HW_OFF);
  const float hw0 = hwv[0], hw1 = hwv[1], hw2 = hwv[2];

  const float* xr0 = x + (size_t)(row0 + lm) * FEATX;
  const float* xr1 = x + (size_t)(row0 + 16 + lm) * FEATX;
  const int*   ir0 = apps + (size_t)(row0 + lm) * NNODES;
  const int*   ir1 = apps + (size_t)(row0 + 16 + lm) * NNODES;
  const char*  w1p = ws + W1P_OFF;

  const f32x4 zed = {0.f, 0.f, 0.f, 0.f};
  f32x4 acc[2][8];
#pragma unroll
  for (int rt = 0; rt < 2; ++rt)
#pragma unroll
    for (int f = 0; f < 8; ++f) acc[rt][f] = zed;

  f16x8 B0[8], B1[8];
  uint4 A0[4], A1[4];
  f16x8 af[2];

  auto LB = [&](int c, f16x8* B) {
    const char* p = w1p + (size_t)(c > NC - 1 ? NC - 1 : c) * 8192 + l * 16;
#pragma unroll
    for (int f = 0; f < 8; ++f) B[f] = *(const f16x8*)(p + f * 1024);
  };
  auto LA = [&](int c, uint4* A) {
    const int k0 = (c > NC - 1 ? NC - 1 : c) * 32 + lg * 8;
    const char *p0, *p1;
    if (k0 + 8 <= FEATX) { p0 = (const char*)(xr0 + k0); p1 = (const char*)(xr1 + k0); }
    else if (k0 < FEAT)  { p0 = (const char*)(ir0 + (k0 - FEATX)); p1 = (const char*)(ir1 + (k0 - FEATX)); }
    else                 { p0 = (const char*)xr0; p1 = (const char*)xr1; }
    A[0] = *(const uint4*)p0; A[1] = *(const uint4*)(p0 + 16);
    A[2] = *(const uint4*)p1; A[3] = *(const uint4*)(p1 + 16);
  };
  auto CV = [&](int c, const uint4* A, f16x8* a2) {
    const int k0 = c * 32 + lg * 8;
#pragma unroll
    for (int rt = 0; rt < 2; ++rt) {
      union { uint4 u[2]; unsigned ui[8]; float f[8]; } d;
      d.u[0] = A[rt * 2]; d.u[1] = A[rt * 2 + 1];
      union { f16x8 v; f16 h[8]; } r;
      if (k0 + 8 <= FEATX) {
#pragma unroll
        for (int j = 0; j < 8; ++j) r.h[j] = (f16)d.f[j];
      } else if (k0 < FEAT) {
#pragma unroll
        for (int j = 0; j < 8; ++j) {
          const unsigned a = d.ui[j];
          r.h[j] = (f16)(a == 0u ? hw0 : (a == 1u ? hw1 : hw2));
        }
      } else {
#pragma unroll
        for (int j = 0; j < 8; ++j) r.h[j] = (f16)0.f;
      }
      a2[rt] = r.v;
    }
  };
  auto MM = [&](const f16x8* a2, const f16x8* B) {
#pragma unroll
    for (int f = 0; f < 8; ++f) {
      acc[0][f] = __builtin_amdgcn_mfma_f32_16x16x32_f16(a2[0], B[f], acc[0][f], 0, 0, 0);
      acc[1][f] = __builtin_amdgcn_mfma_f32_16x16x32_f16(a2[1], B[f], acc[1][f], 0, 0, 0);
    }
  };

  // prologue
  LA(0, A0); LB(0, B0); LA(1, A1);
#pragma unroll 1
  for (int c = 0; c < NC; c += 2) {
    LB(c + 1, B1);
    CV(c, A0, af);
    LA(c + 2, A0);
    MM(af, B0);
    LB(c + 2, B0);
    CV(c + 1, A1, af);
    LA(c + 3, A1);
    MM(af, B1);
  }

  // -------- epilogue 1: + b1', softplus -> LDS a1 f16 [32][128] swizzled --------
  const float* b1p = (const float*)(ws + B1P_OFF);
#pragma unroll
  for (int f = 0; f < 8; ++f) {
    const int col = f * 16 + lm;
    const float bb = b1p[col];
#pragma unroll
    for (int rt = 0; rt < 2; ++rt)
#pragma unroll
      for (int r = 0; r < 4; ++r) {
        const int row = rt * 16 + lg * 4 + r;
        float v = acc[rt][f][r] + bb;
        v = fmaxf(v, 0.f) + log1pf(expf(-fabsf(v)));
        *(f16*)(lds + ((row * 256 + col * 2) ^ ((row & 7) << 4))) = (f16)v;
      }
  }

  // -------- GEMM2: a1 @ W2 (packed frags from L2), softplus -> LDS --------
  f32x4 c2[2][8];
#pragma unroll
  for (int rt = 0; rt < 2; ++rt)
#pragma unroll
    for (int f = 0; f < 8; ++f) c2[rt][f] = zed;
  const char* w2p = ws + W2P_OFF;
#pragma unroll
  for (int ks = 0; ks < 4; ++ks) {
    f16x8 bb2[8];
#pragma unroll
    for (int f = 0; f < 8; ++f)
      bb2[f] = *(const f16x8*)(w2p + ks * 8192 + f * 1024 + l * 16);
    f16x8 a2[2];
#pragma unroll
    for (int rt = 0; rt < 2; ++rt) {
      const int row = rt * 16 + lm;
      a2[rt] = *(const f16x8*)(lds + ((row * 256 + ks * 64 + lg * 16) ^ ((row & 7) << 4)));
    }
#pragma unroll
    for (int f = 0; f < 8; ++f) {
      c2[0][f] = __builtin_amdgcn_mfma_f32_16x16x32_f16(a2[0], bb2[f], c2[0][f], 0, 0, 0);
      c2[1][f] = __builtin_amdgcn_mfma_f32_16x16x32_f16(a2[1], bb2[f], c2[1][f], 0, 0, 0);
    }
  }
#pragma unroll
  for (int f = 0; f < 8; ++f) {
    const int col = f * 16 + lm;
    const float bb = b2[col];
#pragma unroll
    for (int rt = 0; rt < 2; ++rt)
#pragma unroll
      for (int r = 0; r < 4; ++r) {
        const int row = rt * 16 + lg * 4 + r;
        float v = c2[rt][f][r] + bb;
        v = fmaxf(v, 0.f) + log1pf(expf(-fabsf(v)));
        *(f16*)(lds + ((row * 256 + col * 2) ^ ((row & 7) << 4))) = (f16)v;
      }
  }

  // -------- GEMM3: a2 @ W3, tanhshrink -> LDS f32 [32][64] swizzled --------
  f32x4 c3[2][4];
#pragma unroll
  for (int rt = 0; rt < 2; ++rt)
#pragma unroll
    for (int f = 0; f < 4; ++f) c3[rt][f] = zed;
  const char* w3p = ws + W3P_OFF;
#pragma unroll
  for (int ks = 0; ks < 4; ++ks) {
    f16x8 bb3[4];
#pragma unroll
    for (int f = 0; f < 4; ++f)
      bb3[f] = *(const f16x8*)(w3p + ks * 4096 + f * 1024 + l * 16);
    f16x8 a3[2];
#pragma unroll
    for (int rt = 0; rt < 2; ++rt) {
      const int row = rt * 16 + lm;
      a3[rt] = *(const f16x8*)(lds + ((row * 256 + ks * 64 + lg * 16) ^ ((row & 7) << 4)));
    }
#pragma unroll
    for (int f = 0; f < 4; ++f) {
      c3[0][f] = __builtin_amdgcn_mfma_f32_16x16x32_f16(a3[0], bb3[f], c3[0][f], 0, 0, 0);
      c3[1][f] = __builtin_amdgcn_mfma_f32_16x16x32_f16(a3[1], bb3[f], c3[1][f], 0, 0, 0);
    }
  }
#pragma unroll
  for (int f = 0; f < 4; ++f) {
    const int col = f * 16 + lm;
    const float bb = b3[col];
#pragma unroll
    for (int rt = 0; rt < 2; ++rt)
#pragma unroll
      for (int r = 0; r < 4; ++r) {
        const int row = rt * 16 + lg * 4 + r;
        const float z = c3[rt][f][r] + bb;
        *(float*)(lds + ((row * 256 + col * 4) ^ ((row & 7) << 4))) = z - tanhf(z);
      }
  }

  // -------- GEMM4 (vector): a3[32x64] @ W4[64x2] + b4, sigmoid --------
  {
    const int row = l >> 1, j = l & 1;
    float s = 0.f;
#pragma unroll
    for (int kk = 0; kk < 16; ++kk) {
      const f32x4 a = *(const f32x4*)(lds + ((row * 256 + kk * 16) ^ ((row & 7) << 4)));
      s += a[0] * W4[(kk * 4 + 0) * 2 + j] + a[1] * W4[(kk * 4 + 1) * 2 + j]
         + a[2] * W4[(kk * 4 + 2) * 2 + j] + a[3] * W4[(kk * 4 + 3) * 2 + j];
    }
    s += b4[j];
    out[(size_t)(row0 + row) * 2 + j] = 1.f / (1.f + expf(-s));
  }
}

// ---------------- launch ----------------
extern "C" void kernel_launch(void* const* d_in, const int* in_sizes, int n_in,
                              void* d_out, int out_size, void* d_ws, size_t ws_size,
                              hipStream_t stream) {
  const float* x    = (const float*)d_in[0];
  const int*   apps = (const int*)d_in[1];
  const int*   esrc = (const int*)d_in[2];
  const int*   edst = (const int*)d_in[3];
  const float* emb  = (const float*)d_in[4];
  const float* gcw  = (const float*)d_in[5];
  const float* gcb  = (const float*)d_in[6];
  const float* W1   = (const float*)d_in[7];
  const float* b1   = (const float*)d_in[8];
  const float* W2   = (const float*)d_in[9];
  const float* b2   = (const float*)d_in[10];
  const float* W3   = (const float*)d_in[11];
  const float* b3   = (const float*)d_in[12];
  const float* W4   = (const float*)d_in[13];
  const float* b4   = (const float*)d_in[14];
  char* ws = (char*)d_ws;
  float* out = (float*)d_out;

  hipLaunchKernelGGL(prepA, dim3(1), dim3(256), 0, stream,
                     esrc, edst, emb, gcw, gcb, W1, b1, ws);
  hipLaunchKernelGGL(prepWg, dim3(200), dim3(128), 0, stream, W1, ws);
  hipLaunchKernelGGL(pack, dim3(96), dim3(256), 0, stream, W1, W2, W3, ws);
  hipLaunchKernelGGL(fused_main, dim3(512), dim3(64), 0, stream,
                     x, apps, ws, b2, b3, W4, b4, out);
}